// Round 5
// baseline (2147.532 us; speedup 1.0000x reference)
//
#include <hip/hip_runtime.h>
#include <stdint.h>

#define NROWS 16384
#define KCODES 8192
#define DDIM 256
#define OUT_LOSS 4194304
#define OUT_CODES 4194305

// ---- fallback (R3) tile params ----
#define BM 128
#define BN 128
#define BK 16
#define LDT 132

// ---- MFMA path params ----
// bf16 dot error bound (deterministic): 2^-8 * ||z_row|| * ||emb_row||
//   <= 2^-8 * 19.2 * 1.95e-3 ~= 1.5e-4. Need margin >= 2*err + quantum ~ 2.3e-4.
#define MARGIN 3.5e-4f
#define CAP_ENTRIES (6u * 1024u * 1024u)

// ws layout (bytes)
#define WS_BEST  0u
#define WS_X2    131072u
#define WS_GMAX  196608u
#define WS_CNT   262144u
#define WS_ENT   262400u
#define WS_ZEB   50594048u               // WS_ENT + 6M*8
#define WS_EMBB  58982656u               // WS_ZEB + 16384*256*2
#define WS_NEED  63176960u               // WS_EMBB + 8192*256*2

typedef __attribute__((ext_vector_type(8))) short bf16x8;
typedef __attribute__((ext_vector_type(4))) float f32x4;
typedef __attribute__((ext_vector_type(8))) unsigned short u16x8;

__device__ __forceinline__ void async16(const void* g, void* l) {
    __builtin_amdgcn_global_load_lds((const __attribute__((address_space(1))) void*)g,
                                     (__attribute__((address_space(3))) void*)l, 16, 0, 0);
}
// monotone float<->uint encoding (order-preserving incl. negatives)
__device__ __forceinline__ unsigned fenc(float f) {
    unsigned u = __float_as_uint(f);
    return (u & 0x80000000u) ? ~u : (u | 0x80000000u);
}
__device__ __forceinline__ float fdec(unsigned e) {
    unsigned u = (e & 0x80000000u) ? (e ^ 0x80000000u) : ~e;
    return __uint_as_float(u);
}

// ---------------- prep: x2 per row (numpy pairwise order), init best --------
__global__ __launch_bounds__(256) void vq_prep(const float* __restrict__ z_e,
                                               unsigned long long* __restrict__ best,
                                               float* __restrict__ x2w,
                                               float* __restrict__ out)
{
    const int row = blockIdx.x * 256 + threadIdx.x;
    if (row == 0) out[OUT_LOSS] = 0.0f;
    best[row] = ~0ull;

    const float* rp = z_e + (size_t)row * DDIM;
    float hr[2];
    #pragma unroll
    for (int h = 0; h < 2; ++h) {
        const float* a = rp + h * 128;
        float r[8];
        #pragma unroll
        for (int j = 0; j < 8; ++j) { const float v = a[j]; r[j] = __fmul_rn(v, v); }
        #pragma unroll 1
        for (int i = 8; i < 128; i += 8) {
            #pragma unroll
            for (int j = 0; j < 8; ++j) {
                const float v = a[i + j];
                r[j] = __fadd_rn(r[j], __fmul_rn(v, v));
            }
        }
        hr[h] = __fadd_rn(__fadd_rn(__fadd_rn(r[0], r[1]), __fadd_rn(r[2], r[3])),
                          __fadd_rn(__fadd_rn(r[4], r[5]), __fadd_rn(r[6], r[7])));
    }
    x2w[row] = __fadd_rn(hr[0], hr[1]);
}

// ---------------- init2: gmax + counter (MFMA path only) ---------------------
__global__ __launch_bounds__(256) void vq_init2(unsigned* __restrict__ gmax,
                                                unsigned* __restrict__ cnt)
{
    const int i = blockIdx.x * 256 + threadIdx.x;
    gmax[i] = 0u;              // smaller than fenc(any float)
    if (i == 0) *cnt = 0u;
}

// ---------------- conv: fp32 -> bf16 (RNE), 8 elems/thread -------------------
__global__ __launch_bounds__(256) void vq_conv(const float* __restrict__ src,
                                               unsigned short* __restrict__ dst,
                                               int n8)
{
    const int i = blockIdx.x * 256 + threadIdx.x;
    if (i >= n8) return;
    const float4 a = ((const float4*)src)[i * 2];
    const float4 b = ((const float4*)src)[i * 2 + 1];
    const float v[8] = { a.x, a.y, a.z, a.w, b.x, b.y, b.z, b.w };
    u16x8 r;
    #pragma unroll
    for (int j = 0; j < 8; ++j) {
        const unsigned u = __float_as_uint(v[j]);
        r[j] = (unsigned short)((u + 0x7FFFu + ((u >> 16) & 1u)) >> 16);
    }
    *(u16x8*)(dst + (size_t)i * 8) = r;
}

// ---------------- MFMA approx-dot GEMM + per-row max + candidate append -----
// 128x128 tile, BK=64 chunks, 4 waves (2x2 of 64x64), 16x16x32 bf16 MFMA.
// LDS: row-major [128 rows][64 k] bf16, 16B-chunk XOR swizzle (slot = chunk ^
// (row&7)) -> global_load_lds-contiguous AND conflict-spread ds_read_b128.
__global__ __launch_bounds__(256, 2) void vq_mfma(const unsigned short* __restrict__ zeb,
                                                  const unsigned short* __restrict__ embb,
                                                  unsigned* __restrict__ gmax,
                                                  unsigned* __restrict__ cnt,
                                                  unsigned long long* __restrict__ entries)
{
    __shared__ __align__(16) char As[16384];   // 128 x 64 bf16
    __shared__ __align__(16) char Bs[16384];
    __shared__ unsigned lmax[128];
    __shared__ float sthr[128];

    const int tid  = threadIdx.x;
    const int lane = tid & 63;
    const int wid  = tid >> 6;
    const int wm   = wid >> 1, wn = wid & 1;
    const int row0 = blockIdx.x * 128;
    const int col0 = blockIdx.y * 128;

    if (tid < 128) lmax[tid] = 0u;

    const int srow = lane >> 3;          // row within 8-row group
    const int sq   = lane & 7;           // LDS 16B slot
    const int qd   = sq ^ srow;          // global chunk stored in that slot

    f32x4 acc[4][4];
    #pragma unroll
    for (int i = 0; i < 4; ++i)
        #pragma unroll
        for (int j = 0; j < 4; ++j)
            acc[i][j] = (f32x4){0.f, 0.f, 0.f, 0.f};

    const int m    = lane & 15;
    const int quad = lane >> 4;
    const int m7   = m & 7;

    #pragma unroll 1
    for (int c = 0; c < 4; ++c) {        // K chunks of 64
        __syncthreads();
        #pragma unroll
        for (int s = 0; s < 4; ++s) {
            const int rA = wid * 32 + s * 8 + srow;          // local row 0..127
            async16((const char*)zeb + ((size_t)(row0 + rA) << 9) + (c << 7) + (qd << 4),
                    As + (wid * 32 + s * 8) * 128);
            async16((const char*)embb + ((size_t)(col0 + rA) << 9) + (c << 7) + (qd << 4),
                    Bs + (wid * 32 + s * 8) * 128);
        }
        __syncthreads();

        #pragma unroll
        for (int ks = 0; ks < 2; ++ks) {
            const int qq = (ks << 2) + quad;
            bf16x8 af[4], bfr[4];
            #pragma unroll
            for (int t = 0; t < 4; ++t) {
                af[t]  = *(const bf16x8*)(As + (wm * 64 + t * 16 + m) * 128 + ((qq ^ m7) << 4));
                bfr[t] = *(const bf16x8*)(Bs + (wn * 64 + t * 16 + m) * 128 + ((qq ^ m7) << 4));
            }
            #pragma unroll
            for (int i = 0; i < 4; ++i)
                #pragma unroll
                for (int j = 0; j < 4; ++j)
                    acc[i][j] = __builtin_amdgcn_mfma_f32_16x16x32_bf16(af[i], bfr[j], acc[i][j], 0, 0, 0);
        }
    }

    // C/D layout: col = lane&15 (code), row = quad*4 + reg (z_e row)
    #pragma unroll
    for (int ti = 0; ti < 4; ++ti) {
        #pragma unroll
        for (int reg = 0; reg < 4; ++reg) {
            float v = fmaxf(fmaxf(acc[ti][0][reg], acc[ti][1][reg]),
                            fmaxf(acc[ti][2][reg], acc[ti][3][reg]));
            #pragma unroll
            for (int s = 1; s < 16; s <<= 1)
                v = fmaxf(v, __shfl_xor(v, s, 64));
            if (m == 0) atomicMax(&lmax[wm * 64 + ti * 16 + quad * 4 + reg], fenc(v));
        }
    }
    __syncthreads();
    // merge into global gmax and take threshold from the (stricter) global
    // running max — still a superset of the final-gmax filter since
    // gmax_now <= gmax_final.
    if (tid < 128) {
        const unsigned mine = lmax[tid];
        const unsigned old  = atomicMax(&gmax[row0 + tid], mine);
        const unsigned merged = (old > mine) ? old : mine;
        sthr[tid] = fdec(merged) - MARGIN;
    }
    __syncthreads();

    // append candidates: dot >= running-gmax - MARGIN
    #pragma unroll
    for (int ti = 0; ti < 4; ++ti) {
        #pragma unroll
        for (int reg = 0; reg < 4; ++reg) {
            const int rl = wm * 64 + ti * 16 + quad * 4 + reg;
            const float thr = sthr[rl];
            #pragma unroll
            for (int tj = 0; tj < 4; ++tj) {
                const float d = acc[ti][tj][reg];
                if (d >= thr) {
                    const unsigned idx = atomicAdd(cnt, 1u);
                    if (idx < CAP_ENTRIES) {
                        const unsigned code = col0 + wn * 64 + tj * 16 + m;
                        entries[idx] = ((unsigned long long)__float_as_uint(d) << 32)
                                     | ((unsigned long long)(unsigned)(row0 + rl) << 13)
                                     | (unsigned long long)code;
                    }
                }
            }
        }
    }
}

// ---------------- rescore: exact fp32 dist for surviving candidates ---------
__global__ __launch_bounds__(256) void vq_rescore(const float* __restrict__ z_e,
                                                  const float* __restrict__ emb,
                                                  const float* __restrict__ x2w,
                                                  const unsigned* __restrict__ gmax,
                                                  const unsigned* __restrict__ cnt,
                                                  const unsigned long long* __restrict__ entries,
                                                  unsigned long long* __restrict__ best)
{
    const unsigned c = *cnt;
    const unsigned total = (c < CAP_ENTRIES) ? c : CAP_ENTRIES;
    const unsigned stride = gridDim.x * 256;
    for (unsigned i = blockIdx.x * 256 + threadIdx.x; i < total; i += stride) {
        const unsigned long long e = entries[i];
        const float dapp = __uint_as_float((unsigned)(e >> 32));
        const unsigned row  = (unsigned)(e >> 13) & 16383u;
        const unsigned code = (unsigned)e & 8191u;
        if (dapp < fdec(gmax[row]) - MARGIN) continue;
        const float* zr = z_e + (size_t)row * DDIM;
        const float* er = emb + (size_t)code * DDIM;
        float dot = 0.0f;     // strict sequential fp32 FMA (validated semantics)
        #pragma unroll 8
        for (int d = 0; d < DDIM; ++d) dot = __fmaf_rn(zr[d], er[d], dot);
        const float dist = __fsub_rn(x2w[row], __fmul_rn(2.0f, dot));
        const unsigned long long key =
            ((unsigned long long)__float_as_uint(dist) << 32) | code;
        atomicMin(&best[row], key);
    }
}

// ---------------- fix: exact full scan for any unserved row (parachute) -----
__global__ __launch_bounds__(256) void vq_fix(const float* __restrict__ z_e,
                                              const float* __restrict__ emb,
                                              const float* __restrict__ x2w,
                                              unsigned long long* __restrict__ best)
{
    const int row = blockIdx.x * 256 + threadIdx.x;
    if (best[row] != ~0ull) return;      // normal case: nothing to do
    const float* zr = z_e + (size_t)row * DDIM;
    const float x2v = x2w[row];
    unsigned long long key = ~0ull;
    for (int code = 0; code < KCODES; ++code) {
        const float* er = emb + (size_t)code * DDIM;
        float dot = 0.0f;
        #pragma unroll 8
        for (int d = 0; d < DDIM; ++d) dot = __fmaf_rn(zr[d], er[d], dot);
        const float dist = __fsub_rn(x2v, __fmul_rn(2.0f, dot));
        const unsigned long long k2 =
            ((unsigned long long)__float_as_uint(dist) << 32) | (unsigned)code;
        key = (k2 < key) ? k2 : key;
    }
    best[row] = key;
}

// ---------------- fallback (R3): fp32 SGEMM distance + argmin ----------------
__global__ __launch_bounds__(256, 2) void vq_gemm(const float* __restrict__ z_e,
                                                  const float* __restrict__ emb,
                                                  const float* __restrict__ x2w,
                                                  unsigned long long* __restrict__ best)
{
    __shared__ float Asf[BK][LDT];
    __shared__ float Bsf[BK][LDT];
    __shared__ unsigned long long bestL[BM];

    const int tid  = threadIdx.x;
    const int row0 = blockIdx.x * BM;
    const int kc0  = blockIdx.y * BN;
    const int tx   = tid & 15;
    const int ty   = tid >> 4;

    if (tid < BM) bestL[tid] = ~0ull;

    const int sr = tid >> 2;
    const int sd = (tid & 3) * 4;
    const float* aG0 = z_e + (size_t)(row0 + sr) * DDIM + sd;
    const float* aG1 = z_e + (size_t)(row0 + sr + 64) * DDIM + sd;
    const float* bG0 = emb + (size_t)(kc0 + sr) * DDIM + sd;
    const float* bG1 = emb + (size_t)(kc0 + sr + 64) * DDIM + sd;

    float4 pa0 = *(const float4*)(aG0);
    float4 pa1 = *(const float4*)(aG1);
    float4 pb0 = *(const float4*)(bG0);
    float4 pb1 = *(const float4*)(bG1);

    float acc[8][8];
    #pragma unroll
    for (int i = 0; i < 8; ++i)
        #pragma unroll
        for (int j = 0; j < 8; ++j) acc[i][j] = 0.0f;

    #pragma unroll 1
    for (int c = 0; c < DDIM / BK; ++c) {
        __syncthreads();
        Asf[sd + 0][sr]      = pa0.x;  Asf[sd + 1][sr]      = pa0.y;
        Asf[sd + 2][sr]      = pa0.z;  Asf[sd + 3][sr]      = pa0.w;
        Asf[sd + 0][sr + 64] = pa1.x;  Asf[sd + 1][sr + 64] = pa1.y;
        Asf[sd + 2][sr + 64] = pa1.z;  Asf[sd + 3][sr + 64] = pa1.w;
        Bsf[sd + 0][sr]      = pb0.x;  Bsf[sd + 1][sr]      = pb0.y;
        Bsf[sd + 2][sr]      = pb0.z;  Bsf[sd + 3][sr]      = pb0.w;
        Bsf[sd + 0][sr + 64] = pb1.x;  Bsf[sd + 1][sr + 64] = pb1.y;
        Bsf[sd + 2][sr + 64] = pb1.z;  Bsf[sd + 3][sr + 64] = pb1.w;
        __syncthreads();

        if (c + 1 < DDIM / BK) {
            const int off = (c + 1) * BK;
            pa0 = *(const float4*)(aG0 + off);
            pa1 = *(const float4*)(aG1 + off);
            pb0 = *(const float4*)(bG0 + off);
            pb1 = *(const float4*)(bG1 + off);
        }

        #pragma unroll
        for (int d = 0; d < BK; ++d) {
            const float4 a0 = *(const float4*)&Asf[d][ty * 4];
            const float4 a1 = *(const float4*)&Asf[d][ty * 4 + 64];
            const float4 b0 = *(const float4*)&Bsf[d][tx * 4];
            const float4 b1 = *(const float4*)&Bsf[d][tx * 4 + 64];
            const float av[8] = { a0.x, a0.y, a0.z, a0.w, a1.x, a1.y, a1.z, a1.w };
            const float bv[8] = { b0.x, b0.y, b0.z, b0.w, b1.x, b1.y, b1.z, b1.w };
            #pragma unroll
            for (int i = 0; i < 8; ++i)
                #pragma unroll
                for (int j = 0; j < 8; ++j)
                    acc[i][j] = __fmaf_rn(av[i], bv[j], acc[i][j]);
        }
    }

    #pragma unroll
    for (int i = 0; i < 8; ++i) {
        const int r = (i < 4) ? (ty * 4 + i) : (64 + ty * 4 + i - 4);
        const float x2v = x2w[row0 + r];
        unsigned long long key = ~0ull;
        #pragma unroll
        for (int j = 0; j < 8; ++j) {
            const int code = kc0 + ((j < 4) ? (tx * 4 + j) : (64 + tx * 4 + j - 4));
            const float dist = __fsub_rn(x2v, __fmul_rn(2.0f, acc[i][j]));
            const unsigned long long k2 =
                ((unsigned long long)__float_as_uint(dist) << 32) | (unsigned)code;
            key = (k2 < key) ? k2 : key;
        }
        atomicMin(&bestL[r], key);
    }
    __syncthreads();
    if (tid < BM) atomicMin(&best[row0 + tid], bestL[tid]);
}

// ---------------- epilogue: gather z_q, z_q_st, codes, loss ------------------
__global__ __launch_bounds__(256) void vq_epilogue(const float* __restrict__ z_e,
                                                   const float* __restrict__ emb,
                                                   const unsigned long long* __restrict__ best,
                                                   float* __restrict__ out)
{
    const int tid = threadIdx.x;
    float lsum = 0.0f;

    #pragma unroll 1
    for (int r = 0; r < 32; ++r) {
        const int row = blockIdx.x * 32 + r;
        const unsigned code = (unsigned)(best[row]) & 8191u;  // defensive mask
        const float zq = emb[(size_t)code * DDIM + tid];
        const float ze = z_e[(size_t)row * DDIM + tid];
        const float diff = __fsub_rn(zq, ze);
        out[(size_t)row * DDIM + tid] = __fadd_rn(ze, diff);  // z_q_st
        lsum = __fmaf_rn(diff, diff, lsum);
        if (tid == 0) out[OUT_CODES + row] = (float)code;
    }

    #pragma unroll
    for (int o = 32; o > 0; o >>= 1) lsum += __shfl_down(lsum, o);
    __shared__ float wsum[4];
    if ((tid & 63) == 0) wsum[tid >> 6] = lsum;
    __syncthreads();
    if (tid == 0) {
        const float s = (wsum[0] + wsum[1]) + (wsum[2] + wsum[3]);
        atomicAdd(&out[OUT_LOSS], s * (1.25f / 4194304.0f));
    }
}

extern "C" void kernel_launch(void* const* d_in, const int* in_sizes, int n_in,
                              void* d_out, int out_size, void* d_ws, size_t ws_size,
                              hipStream_t stream) {
    const float* z_e = (const float*)d_in[0];
    const float* emb = (const float*)d_in[1];
    float* out = (float*)d_out;
    char* ws = (char*)d_ws;
    unsigned long long* best = (unsigned long long*)(ws + WS_BEST);
    float* x2w = (float*)(ws + WS_X2);
    (void)in_sizes; (void)n_in; (void)out_size;

    vq_prep<<<dim3(NROWS / 256), dim3(256), 0, stream>>>(z_e, best, x2w, out);

    if (ws_size >= (size_t)WS_NEED) {
        unsigned* gmax = (unsigned*)(ws + WS_GMAX);
        unsigned* cnt  = (unsigned*)(ws + WS_CNT);
        unsigned long long* entries = (unsigned long long*)(ws + WS_ENT);
        unsigned short* zeb  = (unsigned short*)(ws + WS_ZEB);
        unsigned short* embb = (unsigned short*)(ws + WS_EMBB);

        vq_init2<<<dim3(NROWS / 256), dim3(256), 0, stream>>>(gmax, cnt);
        vq_conv<<<dim3(NROWS * DDIM / (256 * 8)), dim3(256), 0, stream>>>(z_e, zeb, NROWS * DDIM / 8);
        vq_conv<<<dim3(KCODES * DDIM / (256 * 8)), dim3(256), 0, stream>>>(emb, embb, KCODES * DDIM / 8);
        vq_mfma<<<dim3(NROWS / 128, KCODES / 128), dim3(256), 0, stream>>>(zeb, embb, gmax, cnt, entries);
        vq_rescore<<<dim3(1024), dim3(256), 0, stream>>>(z_e, emb, x2w, gmax, cnt, entries, best);
        vq_fix<<<dim3(NROWS / 256), dim3(256), 0, stream>>>(z_e, emb, x2w, best);
    } else {
        vq_gemm<<<dim3(NROWS / BM, KCODES / BN), dim3(256), 0, stream>>>(z_e, emb, x2w, best);
    }

    vq_epilogue<<<dim3(NROWS / 32), dim3(256), 0, stream>>>(z_e, emb, best, out);
}

// Round 6
// 300.255 us; speedup vs baseline: 7.1524x; 7.1524x over previous
//
#include <hip/hip_runtime.h>
#include <stdint.h>

#define NROWS 16384
#define KCODES 8192
#define DDIM 256
#define OUT_LOSS 4194304
#define OUT_CODES 4194305

// ---- fallback (R3) tile params ----
#define BM 128
#define BN 128
#define BK 16
#define LDT 132

// ---- MFMA path params ----
// bf16 dot error bound (deterministic): 2^-8 * ||z_row|| * ||emb_row||
//   <= 2^-8 * 19.2 * 1.95e-3 ~= 1.5e-4. Need margin >= 2*err + quantum ~ 2.3e-4.
#define MARGIN 3.5e-4f
#define CAP_ENTRIES (6u * 1024u * 1024u)
#define LCAP 2048u

// ws layout (bytes)
#define WS_BEST  0u
#define WS_X2    131072u
#define WS_GMAX  196608u
#define WS_CNT   262144u
#define WS_BAD   262400u                 // 16384 x u8 row-overflow flags
#define WS_ENT   278784u
#define WS_ZEB   50610432u               // WS_ENT + 6M*8
#define WS_EMBB  58999040u               // WS_ZEB + 16384*256*2
#define WS_NEED  63193344u               // WS_EMBB + 8192*256*2

typedef __attribute__((ext_vector_type(8))) short bf16x8;
typedef __attribute__((ext_vector_type(4))) float f32x4;
typedef __attribute__((ext_vector_type(8))) unsigned short u16x8;

__device__ __forceinline__ void async16(const void* g, void* l) {
    __builtin_amdgcn_global_load_lds((const __attribute__((address_space(1))) void*)g,
                                     (__attribute__((address_space(3))) void*)l, 16, 0, 0);
}
// monotone float<->uint encoding (order-preserving incl. negatives)
__device__ __forceinline__ unsigned fenc(float f) {
    unsigned u = __float_as_uint(f);
    return (u & 0x80000000u) ? ~u : (u | 0x80000000u);
}
__device__ __forceinline__ float fdec(unsigned e) {
    unsigned u = (e & 0x80000000u) ? (e ^ 0x80000000u) : ~e;
    return __uint_as_float(u);
}

// ---------------- prep: x2 per row (numpy pairwise order), init best --------
__global__ __launch_bounds__(256) void vq_prep(const float* __restrict__ z_e,
                                               unsigned long long* __restrict__ best,
                                               float* __restrict__ x2w,
                                               float* __restrict__ out)
{
    const int row = blockIdx.x * 256 + threadIdx.x;
    if (row == 0) out[OUT_LOSS] = 0.0f;
    best[row] = ~0ull;

    const float* rp = z_e + (size_t)row * DDIM;
    float hr[2];
    #pragma unroll
    for (int h = 0; h < 2; ++h) {
        const float* a = rp + h * 128;
        float r[8];
        #pragma unroll
        for (int j = 0; j < 8; ++j) { const float v = a[j]; r[j] = __fmul_rn(v, v); }
        #pragma unroll 1
        for (int i = 8; i < 128; i += 8) {
            #pragma unroll
            for (int j = 0; j < 8; ++j) {
                const float v = a[i + j];
                r[j] = __fadd_rn(r[j], __fmul_rn(v, v));
            }
        }
        hr[h] = __fadd_rn(__fadd_rn(__fadd_rn(r[0], r[1]), __fadd_rn(r[2], r[3])),
                          __fadd_rn(__fadd_rn(r[4], r[5]), __fadd_rn(r[6], r[7])));
    }
    x2w[row] = __fadd_rn(hr[0], hr[1]);
}

// ---------------- init2: gmax + counter + bad flags (MFMA path only) --------
__global__ __launch_bounds__(256) void vq_init2(unsigned* __restrict__ gmax,
                                                unsigned* __restrict__ cnt,
                                                unsigned char* __restrict__ bad)
{
    const int i = blockIdx.x * 256 + threadIdx.x;
    gmax[i] = 0u;              // smaller than fenc(any float)
    bad[i] = 0;
    if (i == 0) *cnt = 0u;
}

// ---------------- conv: fp32 -> bf16 (RNE), 8 elems/thread -------------------
__global__ __launch_bounds__(256) void vq_conv(const float* __restrict__ src,
                                               unsigned short* __restrict__ dst,
                                               int n8)
{
    const int i = blockIdx.x * 256 + threadIdx.x;
    if (i >= n8) return;
    const float4 a = ((const float4*)src)[i * 2];
    const float4 b = ((const float4*)src)[i * 2 + 1];
    const float v[8] = { a.x, a.y, a.z, a.w, b.x, b.y, b.z, b.w };
    u16x8 r;
    #pragma unroll
    for (int j = 0; j < 8; ++j) {
        const unsigned u = __float_as_uint(v[j]);
        r[j] = (unsigned short)((u + 0x7FFFu + ((u >> 16) & 1u)) >> 16);
    }
    *(u16x8*)(dst + (size_t)i * 8) = r;
}

// ---------------- MFMA approx-dot GEMM + per-row max + candidate append -----
// 128x128 tile, BK=64 chunks, 4 waves (2x2 of 64x64), 16x16x32 bf16 MFMA.
// LDS: row-major [128 rows][64 k] bf16, 16B-chunk XOR swizzle (slot = chunk ^
// (row&7)) -> global_load_lds-contiguous AND conflict-spread ds_read_b128.
// Candidate appends go through an LDS slab (As reused) + ONE global
// atomicAdd per block — R5's per-candidate global counter serialized the
// whole GPU on a single cacheline (2 ms, all pipes idle).
__global__ __launch_bounds__(256, 2) void vq_mfma(const unsigned short* __restrict__ zeb,
                                                  const unsigned short* __restrict__ embb,
                                                  unsigned* __restrict__ gmax,
                                                  unsigned* __restrict__ cnt,
                                                  unsigned long long* __restrict__ entries,
                                                  unsigned char* __restrict__ bad)
{
    __shared__ __align__(16) char As[16384];   // 128 x 64 bf16; reused as cbuf
    __shared__ __align__(16) char Bs[16384];
    __shared__ unsigned lmax[128];
    __shared__ float sthr[128];
    __shared__ unsigned lcnt, gbase;

    const int tid  = threadIdx.x;
    const int lane = tid & 63;
    const int wid  = tid >> 6;
    const int wm   = wid >> 1, wn = wid & 1;
    const int row0 = blockIdx.x * 128;
    const int col0 = blockIdx.y * 128;

    if (tid < 128) lmax[tid] = 0u;
    if (tid == 0) lcnt = 0u;

    const int srow = lane >> 3;          // row within 8-row group
    const int sq   = lane & 7;           // LDS 16B slot
    const int qd   = sq ^ srow;          // global chunk stored in that slot

    f32x4 acc[4][4];
    #pragma unroll
    for (int i = 0; i < 4; ++i)
        #pragma unroll
        for (int j = 0; j < 4; ++j)
            acc[i][j] = (f32x4){0.f, 0.f, 0.f, 0.f};

    const int m    = lane & 15;
    const int quad = lane >> 4;
    const int m7   = m & 7;

    #pragma unroll 1
    for (int c = 0; c < 4; ++c) {        // K chunks of 64
        __syncthreads();
        #pragma unroll
        for (int s = 0; s < 4; ++s) {
            const int rA = wid * 32 + s * 8 + srow;          // local row 0..127
            async16((const char*)zeb + ((size_t)(row0 + rA) << 9) + (c << 7) + (qd << 4),
                    As + (wid * 32 + s * 8) * 128);
            async16((const char*)embb + ((size_t)(col0 + rA) << 9) + (c << 7) + (qd << 4),
                    Bs + (wid * 32 + s * 8) * 128);
        }
        __syncthreads();

        #pragma unroll
        for (int ks = 0; ks < 2; ++ks) {
            const int qq = (ks << 2) + quad;
            bf16x8 af[4], bfr[4];
            #pragma unroll
            for (int t = 0; t < 4; ++t) {
                af[t]  = *(const bf16x8*)(As + (wm * 64 + t * 16 + m) * 128 + ((qq ^ m7) << 4));
                bfr[t] = *(const bf16x8*)(Bs + (wn * 64 + t * 16 + m) * 128 + ((qq ^ m7) << 4));
            }
            #pragma unroll
            for (int i = 0; i < 4; ++i)
                #pragma unroll
                for (int j = 0; j < 4; ++j)
                    acc[i][j] = __builtin_amdgcn_mfma_f32_16x16x32_bf16(af[i], bfr[j], acc[i][j], 0, 0, 0);
        }
    }

    // C/D layout: col = lane&15 (code), row = quad*4 + reg (z_e row)
    #pragma unroll
    for (int ti = 0; ti < 4; ++ti) {
        #pragma unroll
        for (int reg = 0; reg < 4; ++reg) {
            float v = fmaxf(fmaxf(acc[ti][0][reg], acc[ti][1][reg]),
                            fmaxf(acc[ti][2][reg], acc[ti][3][reg]));
            #pragma unroll
            for (int s = 1; s < 16; s <<= 1)
                v = fmaxf(v, __shfl_xor(v, s, 64));
            if (m == 0) atomicMax(&lmax[wm * 64 + ti * 16 + quad * 4 + reg], fenc(v));
        }
    }
    __syncthreads();
    // merge into global gmax; threshold from the (stricter) running global max
    // — still a superset of the final-gmax filter since gmax_now <= gmax_final.
    if (tid < 128) {
        const unsigned mine = lmax[tid];
        const unsigned old  = atomicMax(&gmax[row0 + tid], mine);
        const unsigned merged = (old > mine) ? old : mine;
        sthr[tid] = fdec(merged) - MARGIN;
    }
    __syncthreads();   // also: all ds_reads of As done -> safe to reuse as cbuf

    unsigned long long* cbuf = (unsigned long long*)As;   // 2048-entry slab

    // append candidates: dot >= running-gmax - MARGIN, into LDS slab
    #pragma unroll
    for (int ti = 0; ti < 4; ++ti) {
        #pragma unroll
        for (int reg = 0; reg < 4; ++reg) {
            const int rl = wm * 64 + ti * 16 + quad * 4 + reg;
            const float thr = sthr[rl];
            #pragma unroll
            for (int tj = 0; tj < 4; ++tj) {
                const float d = acc[ti][tj][reg];
                if (d >= thr) {
                    const unsigned code = col0 + wn * 64 + tj * 16 + m;
                    const unsigned long long ent =
                        ((unsigned long long)__float_as_uint(d) << 32)
                        | ((unsigned long long)(unsigned)(row0 + rl) << 13)
                        | (unsigned long long)code;
                    const unsigned li = atomicAdd(&lcnt, 1u);
                    if (li < LCAP) {
                        cbuf[li] = ent;
                    } else {                       // LDS overflow: rare slow path
                        const unsigned gi = atomicAdd(cnt, 1u);
                        if (gi < CAP_ENTRIES) entries[gi] = ent;
                        else bad[row0 + rl] = 1;   // airtight parachute
                    }
                }
            }
        }
    }
    __syncthreads();
    const unsigned n = (lcnt < LCAP) ? lcnt : LCAP;
    if (tid == 0) gbase = atomicAdd(cnt, n);       // ONE global atomic per block
    __syncthreads();
    const unsigned base = gbase;
    for (unsigned i = tid; i < n; i += 256) {
        const unsigned long long ent = cbuf[i];
        const unsigned gi = base + i;
        if (gi < CAP_ENTRIES) entries[gi] = ent;
        else bad[(unsigned)(ent >> 13) & 16383u] = 1;
    }
}

// ---------------- rescore: exact fp32 dist for surviving candidates ---------
__global__ __launch_bounds__(256) void vq_rescore(const float* __restrict__ z_e,
                                                  const float* __restrict__ emb,
                                                  const float* __restrict__ x2w,
                                                  const unsigned* __restrict__ gmax,
                                                  const unsigned* __restrict__ cnt,
                                                  const unsigned long long* __restrict__ entries,
                                                  unsigned long long* __restrict__ best)
{
    const unsigned c = *cnt;
    const unsigned total = (c < CAP_ENTRIES) ? c : CAP_ENTRIES;
    const unsigned stride = gridDim.x * 256;
    for (unsigned i = blockIdx.x * 256 + threadIdx.x; i < total; i += stride) {
        const unsigned long long e = entries[i];
        const float dapp = __uint_as_float((unsigned)(e >> 32));
        const unsigned row  = (unsigned)(e >> 13) & 16383u;
        const unsigned code = (unsigned)e & 8191u;
        if (dapp < fdec(gmax[row]) - MARGIN) continue;
        const float* zr = z_e + (size_t)row * DDIM;
        const float* er = emb + (size_t)code * DDIM;
        float dot = 0.0f;     // strict sequential fp32 FMA (validated semantics)
        #pragma unroll 8
        for (int d = 0; d < DDIM; ++d) dot = __fmaf_rn(zr[d], er[d], dot);
        const float dist = __fsub_rn(x2w[row], __fmul_rn(2.0f, dot));
        const unsigned long long key =
            ((unsigned long long)__float_as_uint(dist) << 32) | code;
        atomicMin(&best[row], key);
    }
}

// ---------------- fix: exact full scan for any unserved/overflowed row ------
__global__ __launch_bounds__(256) void vq_fix(const float* __restrict__ z_e,
                                              const float* __restrict__ emb,
                                              const float* __restrict__ x2w,
                                              const unsigned char* __restrict__ bad,
                                              unsigned long long* __restrict__ best)
{
    const int row = blockIdx.x * 256 + threadIdx.x;
    if (best[row] != ~0ull && !bad[row]) return;   // normal case: nothing to do
    const float* zr = z_e + (size_t)row * DDIM;
    const float x2v = x2w[row];
    unsigned long long key = ~0ull;
    for (int code = 0; code < KCODES; ++code) {
        const float* er = emb + (size_t)code * DDIM;
        float dot = 0.0f;
        #pragma unroll 8
        for (int d = 0; d < DDIM; ++d) dot = __fmaf_rn(zr[d], er[d], dot);
        const float dist = __fsub_rn(x2v, __fmul_rn(2.0f, dot));
        const unsigned long long k2 =
            ((unsigned long long)__float_as_uint(dist) << 32) | (unsigned)code;
        key = (k2 < key) ? k2 : key;
    }
    best[row] = key;
}

// ---------------- fallback (R3): fp32 SGEMM distance + argmin ----------------
__global__ __launch_bounds__(256, 2) void vq_gemm(const float* __restrict__ z_e,
                                                  const float* __restrict__ emb,
                                                  const float* __restrict__ x2w,
                                                  unsigned long long* __restrict__ best)
{
    __shared__ float Asf[BK][LDT];
    __shared__ float Bsf[BK][LDT];
    __shared__ unsigned long long bestL[BM];

    const int tid  = threadIdx.x;
    const int row0 = blockIdx.x * BM;
    const int kc0  = blockIdx.y * BN;
    const int tx   = tid & 15;
    const int ty   = tid >> 4;

    if (tid < BM) bestL[tid] = ~0ull;

    const int sr = tid >> 2;
    const int sd = (tid & 3) * 4;
    const float* aG0 = z_e + (size_t)(row0 + sr) * DDIM + sd;
    const float* aG1 = z_e + (size_t)(row0 + sr + 64) * DDIM + sd;
    const float* bG0 = emb + (size_t)(kc0 + sr) * DDIM + sd;
    const float* bG1 = emb + (size_t)(kc0 + sr + 64) * DDIM + sd;

    float4 pa0 = *(const float4*)(aG0);
    float4 pa1 = *(const float4*)(aG1);
    float4 pb0 = *(const float4*)(bG0);
    float4 pb1 = *(const float4*)(bG1);

    float acc[8][8];
    #pragma unroll
    for (int i = 0; i < 8; ++i)
        #pragma unroll
        for (int j = 0; j < 8; ++j) acc[i][j] = 0.0f;

    #pragma unroll 1
    for (int c = 0; c < DDIM / BK; ++c) {
        __syncthreads();
        Asf[sd + 0][sr]      = pa0.x;  Asf[sd + 1][sr]      = pa0.y;
        Asf[sd + 2][sr]      = pa0.z;  Asf[sd + 3][sr]      = pa0.w;
        Asf[sd + 0][sr + 64] = pa1.x;  Asf[sd + 1][sr + 64] = pa1.y;
        Asf[sd + 2][sr + 64] = pa1.z;  Asf[sd + 3][sr + 64] = pa1.w;
        Bsf[sd + 0][sr]      = pb0.x;  Bsf[sd + 1][sr]      = pb0.y;
        Bsf[sd + 2][sr]      = pb0.z;  Bsf[sd + 3][sr]      = pb0.w;
        Bsf[sd + 0][sr + 64] = pb1.x;  Bsf[sd + 1][sr + 64] = pb1.y;
        Bsf[sd + 2][sr + 64] = pb1.z;  Bsf[sd + 3][sr + 64] = pb1.w;
        __syncthreads();

        if (c + 1 < DDIM / BK) {
            const int off = (c + 1) * BK;
            pa0 = *(const float4*)(aG0 + off);
            pa1 = *(const float4*)(aG1 + off);
            pb0 = *(const float4*)(bG0 + off);
            pb1 = *(const float4*)(bG1 + off);
        }

        #pragma unroll
        for (int d = 0; d < BK; ++d) {
            const float4 a0 = *(const float4*)&Asf[d][ty * 4];
            const float4 a1 = *(const float4*)&Asf[d][ty * 4 + 64];
            const float4 b0 = *(const float4*)&Bsf[d][tx * 4];
            const float4 b1 = *(const float4*)&Bsf[d][tx * 4 + 64];
            const float av[8] = { a0.x, a0.y, a0.z, a0.w, a1.x, a1.y, a1.z, a1.w };
            const float bv[8] = { b0.x, b0.y, b0.z, b0.w, b1.x, b1.y, b1.z, b1.w };
            #pragma unroll
            for (int i = 0; i < 8; ++i)
                #pragma unroll
                for (int j = 0; j < 8; ++j)
                    acc[i][j] = __fmaf_rn(av[i], bv[j], acc[i][j]);
        }
    }

    #pragma unroll
    for (int i = 0; i < 8; ++i) {
        const int r = (i < 4) ? (ty * 4 + i) : (64 + ty * 4 + i - 4);
        const float x2v = x2w[row0 + r];
        unsigned long long key = ~0ull;
        #pragma unroll
        for (int j = 0; j < 8; ++j) {
            const int code = kc0 + ((j < 4) ? (tx * 4 + j) : (64 + tx * 4 + j - 4));
            const float dist = __fsub_rn(x2v, __fmul_rn(2.0f, acc[i][j]));
            const unsigned long long k2 =
                ((unsigned long long)__float_as_uint(dist) << 32) | (unsigned)code;
            key = (k2 < key) ? k2 : key;
        }
        atomicMin(&bestL[r], key);
    }
    __syncthreads();
    if (tid < BM) atomicMin(&best[row0 + tid], bestL[tid]);
}

// ---------------- epilogue: gather z_q, z_q_st, codes, loss ------------------
__global__ __launch_bounds__(256) void vq_epilogue(const float* __restrict__ z_e,
                                                   const float* __restrict__ emb,
                                                   const unsigned long long* __restrict__ best,
                                                   float* __restrict__ out)
{
    const int tid = threadIdx.x;
    float lsum = 0.0f;

    #pragma unroll 1
    for (int r = 0; r < 32; ++r) {
        const int row = blockIdx.x * 32 + r;
        const unsigned code = (unsigned)(best[row]) & 8191u;  // defensive mask
        const float zq = emb[(size_t)code * DDIM + tid];
        const float ze = z_e[(size_t)row * DDIM + tid];
        const float diff = __fsub_rn(zq, ze);
        out[(size_t)row * DDIM + tid] = __fadd_rn(ze, diff);  // z_q_st
        lsum = __fmaf_rn(diff, diff, lsum);
        if (tid == 0) out[OUT_CODES + row] = (float)code;
    }

    #pragma unroll
    for (int o = 32; o > 0; o >>= 1) lsum += __shfl_down(lsum, o);
    __shared__ float wsum[4];
    if ((tid & 63) == 0) wsum[tid >> 6] = lsum;
    __syncthreads();
    if (tid == 0) {
        const float s = (wsum[0] + wsum[1]) + (wsum[2] + wsum[3]);
        atomicAdd(&out[OUT_LOSS], s * (1.25f / 4194304.0f));
    }
}

extern "C" void kernel_launch(void* const* d_in, const int* in_sizes, int n_in,
                              void* d_out, int out_size, void* d_ws, size_t ws_size,
                              hipStream_t stream) {
    const float* z_e = (const float*)d_in[0];
    const float* emb = (const float*)d_in[1];
    float* out = (float*)d_out;
    char* ws = (char*)d_ws;
    unsigned long long* best = (unsigned long long*)(ws + WS_BEST);
    float* x2w = (float*)(ws + WS_X2);
    (void)in_sizes; (void)n_in; (void)out_size;

    vq_prep<<<dim3(NROWS / 256), dim3(256), 0, stream>>>(z_e, best, x2w, out);

    if (ws_size >= (size_t)WS_NEED) {
        unsigned* gmax = (unsigned*)(ws + WS_GMAX);
        unsigned* cnt  = (unsigned*)(ws + WS_CNT);
        unsigned char* bad = (unsigned char*)(ws + WS_BAD);
        unsigned long long* entries = (unsigned long long*)(ws + WS_ENT);
        unsigned short* zeb  = (unsigned short*)(ws + WS_ZEB);
        unsigned short* embb = (unsigned short*)(ws + WS_EMBB);

        vq_init2<<<dim3(NROWS / 256), dim3(256), 0, stream>>>(gmax, cnt, bad);
        vq_conv<<<dim3(NROWS * DDIM / (256 * 8)), dim3(256), 0, stream>>>(z_e, zeb, NROWS * DDIM / 8);
        vq_conv<<<dim3(KCODES * DDIM / (256 * 8)), dim3(256), 0, stream>>>(emb, embb, KCODES * DDIM / 8);
        vq_mfma<<<dim3(NROWS / 128, KCODES / 128), dim3(256), 0, stream>>>(zeb, embb, gmax, cnt, entries, bad);
        vq_rescore<<<dim3(1024), dim3(256), 0, stream>>>(z_e, emb, x2w, gmax, cnt, entries, best);
        vq_fix<<<dim3(NROWS / 256), dim3(256), 0, stream>>>(z_e, emb, x2w, bad, best);
    } else {
        vq_gemm<<<dim3(NROWS / BM, KCODES / BN), dim3(256), 0, stream>>>(z_e, emb, x2w, best);
    }

    vq_epilogue<<<dim3(NROWS / 32), dim3(256), 0, stream>>>(z_e, emb, best, out);
}